// Round 3
// baseline (1552.798 us; speedup 1.0000x reference)
//
#include <hip/hip_runtime.h>

typedef unsigned long long ULL;

// B=8, Cin=Cout=256, H=W=64, A=9, N=36864/batch, PRE=1000, POST=300

__device__ __forceinline__ ULL fkey64(double f) {
    ULL u = (ULL)__double_as_longlong(f);
    return (u & 0x8000000000000000ull) ? ~u : (u | 0x8000000000000000ull);
}

// ---------------- kernel 1: transpose conv weights to wt[(ci*9+tap)*256 + co] ----------------
__global__ void prep_wt(const float* __restrict__ wconv, float* __restrict__ wt) {
    int e = blockIdx.x * 256 + threadIdx.x;   // 589824 total
    int row = e >> 8;                          // ci*9 + tap
    int co = e & 255;
    int ci = row / 9;
    int tap = row - ci * 9;
    wt[e] = wconv[(co * 256 + ci) * 9 + tap];
}

// ---------------- kernel 2: 3x3 conv + bias + relu, fp64 acc, output NHWC fp64 ---------------
// grid 1024 = 8 b * 64 rows * 2 cogroups; block 256
// block tile: 64 px (1 row) x 128 co; thread tile 4 px x 8 co
__global__ __launch_bounds__(256, 2) void conv3x3_relu_f64(
    const float* __restrict__ xin, const float* __restrict__ wt,
    const float* __restrict__ bias, double* __restrict__ y)
{
    __shared__ float xs[1728];   // 8 cil * 3 rows * 72 (cols -1..64 at idx 0..65)
    __shared__ float wsh[9504];  // 72 k * 33 float4 (swizzled co groups)

    const int t = threadIdx.x;
    const int blk = blockIdx.x;
    const int b = blk >> 7;
    const int h = (blk >> 1) & 63;
    const int cog = blk & 1;
    const int tx = t & 15, ty = t >> 4;
    const int colbase = tx * 4;

    double acc[8][4];
#pragma unroll
    for (int i = 0; i < 8; i++)
#pragma unroll
        for (int j = 0; j < 4; j++) acc[i][j] = 0.0;

    int x_ld[7], x_go[7];
#pragma unroll
    for (int i = 0; i < 7; i++) {
        int e = t + i * 256;
        x_ld[i] = -1; x_go[i] = -1;
        if (e < 1584) {                       // 8 cil * 3 rows * 66 cols
            int cil = e / 198; int rem = e - cil * 198;
            int row = rem / 66; int c = rem - row * 66;
            int hh = h - 1 + row; int col = c - 1;
            x_ld[i] = (cil * 3 + row) * 72 + c;
            if (hh >= 0 && hh < 64 && col >= 0 && col < 64)
                x_go[i] = cil * 4096 + hh * 64 + col;
        }
    }
    int w_ld4[9], w_go4[9];
#pragma unroll
    for (int i = 0; i < 9; i++) {
        int e4 = t + i * 256;                 // 2304 float4 per chunk
        int k = e4 >> 5; int g = e4 & 31;
        int p = ((g & 1) << 4) | (g >> 1);    // swizzle
        w_ld4[i] = k * 33 + p;
        w_go4[i] = k * 64 + cog * 32 + g;
    }

    const float* xb = xin + (size_t)b * 1048576;
    const float4* wt4 = (const float4*)wt;

    for (int cc = 0; cc < 32; cc++) {
        __syncthreads();
#pragma unroll
        for (int i = 0; i < 7; i++)
            if (x_ld[i] >= 0)
                xs[x_ld[i]] = (x_go[i] >= 0) ? xb[cc * 32768 + x_go[i]] : 0.f;
        float4* wsh4w = (float4*)wsh;
#pragma unroll
        for (int i = 0; i < 9; i++)
            wsh4w[w_ld4[i]] = wt4[cc * 4608 + w_go4[i]];
        __syncthreads();

        const float4* wsh4 = (const float4*)wsh;
#pragma unroll
        for (int cil = 0; cil < 8; cil++) {
#pragma unroll
            for (int kh = 0; kh < 3; kh++) {
                const float* xrow = &xs[(cil * 3 + kh) * 72 + colbase];
                float4 xa = *(const float4*)(xrow);
                float4 xb4 = *(const float4*)(xrow + 4);
                double xd[6] = { (double)xa.x, (double)xa.y, (double)xa.z,
                                 (double)xa.w, (double)xb4.x, (double)xb4.y };
#pragma unroll
                for (int kw = 0; kw < 3; kw++) {
                    int k = cil * 9 + kh * 3 + kw;
                    float4 w0 = wsh4[k * 33 + ty];
                    float4 w1 = wsh4[k * 33 + 16 + ty];
                    double wd[8] = { (double)w0.x, (double)w0.y, (double)w0.z, (double)w0.w,
                                     (double)w1.x, (double)w1.y, (double)w1.z, (double)w1.w };
#pragma unroll
                    for (int j = 0; j < 4; j++) {
                        double xv = xd[j + kw];
#pragma unroll
                        for (int i = 0; i < 8; i++)
                            acc[i][j] = fma(wd[i], xv, acc[i][j]);
                    }
                }
            }
        }
    }

    const float* bptr = bias + cog * 128 + ty * 8;
    double bs[8];
#pragma unroll
    for (int i = 0; i < 8; i++) bs[i] = (double)bptr[i];
    double* yb = y + ((size_t)(b * 4096 + h * 64 + colbase)) * 256 + cog * 128 + ty * 8;
#pragma unroll
    for (int j = 0; j < 4; j++) {
        double4 o0, o1;
        o0.x = fmax(acc[0][j] + bs[0], 0.0);
        o0.y = fmax(acc[1][j] + bs[1], 0.0);
        o0.z = fmax(acc[2][j] + bs[2], 0.0);
        o0.w = fmax(acc[3][j] + bs[3], 0.0);
        o1.x = fmax(acc[4][j] + bs[4], 0.0);
        o1.y = fmax(acc[5][j] + bs[5], 0.0);
        o1.z = fmax(acc[6][j] + bs[6], 0.0);
        o1.w = fmax(acc[7][j] + bs[7], 0.0);
        double* yp = yb + (size_t)j * 256;
        *(double4*)yp = o0;
        *((double4*)yp + 1) = o1;
    }
}

// ---------------- kernel 3: clf head fp64, dlog = (l1+b1) - (l0+b0), store fp64 --------------
__global__ __launch_bounds__(64) void head_clf(
    const double* __restrict__ y, const float* __restrict__ wclf,
    const float* __restrict__ bclf, double* __restrict__ dlog)
{
    int gid = blockIdx.x * 64 + threadIdx.x;
    const double4* x4 = (const double4*)(y + (size_t)gid * 256);
    double l0[9], l1[9];
#pragma unroll
    for (int a = 0; a < 9; a++) { l0[a] = 0.0; l1[a] = 0.0; }
#pragma unroll 2
    for (int c4 = 0; c4 < 64; c4++) {
        double4 xv = x4[c4];
#pragma unroll
        for (int a = 0; a < 9; a++) {
            const float* w0 = wclf + a * 256 + c4 * 4;        // wave-uniform
            const float* w1 = wclf + (9 + a) * 256 + c4 * 4;
            l0[a] = fma((double)w0[0], xv.x, l0[a]); l0[a] = fma((double)w0[1], xv.y, l0[a]);
            l0[a] = fma((double)w0[2], xv.z, l0[a]); l0[a] = fma((double)w0[3], xv.w, l0[a]);
            l1[a] = fma((double)w1[0], xv.x, l1[a]); l1[a] = fma((double)w1[1], xv.y, l1[a]);
            l1[a] = fma((double)w1[2], xv.z, l1[a]); l1[a] = fma((double)w1[3], xv.w, l1[a]);
        }
    }
#pragma unroll
    for (int a = 0; a < 9; a++)
        dlog[(size_t)gid * 9 + a] =
            (l1[a] + (double)bclf[9 + a]) - (l0[a] + (double)bclf[a]);
}

// ---------------- kernel 4: exact top-1000 per batch, 64-bit radix select + pair sort --------
__global__ __launch_bounds__(1024) void topk1000(
    const double* __restrict__ dlog, int* __restrict__ selidx)
{
    const int b = blockIdx.x;
    const int t = threadIdx.x;
    const double* d = dlog + (size_t)b * 36864;
    __shared__ unsigned int hist[256];
    __shared__ ULL sh_prefix;
    __shared__ unsigned int sh_need;

    ULL prefix = 0ull;
    int need = 1000;
    for (int rs = 56; rs >= 0; rs -= 8) {
        if (t < 256) hist[t] = 0u;
        __syncthreads();
        ULL mhi = (rs == 56) ? 0ull : (~0ull << (rs + 8));
        for (int i = t; i < 36864; i += 1024) {
            ULL u = fkey64(d[i]);
            if ((u & mhi) == prefix)
                atomicAdd(&hist[(unsigned int)(u >> rs) & 255u], 1u);
        }
        __syncthreads();
        if (t == 0) {
            int cum = 0; int v = 255;
            for (; v > 0; v--) {
                int c = (int)hist[v];
                if (cum + c >= need) break;
                cum += c;
            }
            sh_prefix = prefix | ((ULL)v << rs);
            sh_need = (unsigned int)(need - cum);
        }
        __syncthreads();
        prefix = sh_prefix;
        need = (int)sh_need;
        __syncthreads();
    }

    const ULL K = prefix;                    // exact fp64 key of the 1000th largest
    const int count_above = 1000 - need;     // strictly greater than K
    __shared__ ULL skey[1024];
    __shared__ int sidx[1024];
    __shared__ unsigned int cgt, ceq;
    if (t == 0) { cgt = 0u; ceq = 0u; }
    skey[t] = ~0ull;
    sidx[t] = 0x7FFFFFFF;
    __syncthreads();
    for (int i = t; i < 36864; i += 1024) {
        ULL u = fkey64(d[i]);
        if (u > K) {
            unsigned int s = atomicAdd(&cgt, 1u);
            skey[s] = ~u; sidx[s] = i;
        } else if (u == K) {
            unsigned int s = atomicAdd(&ceq, 1u) + (unsigned int)count_above;
            if (s < 1024u) { skey[s] = ~u; sidx[s] = i; }
        }
    }
    __syncthreads();
    // bitonic sort ascending on (key, idx): == score desc, index asc on ties
    for (int k = 2; k <= 1024; k <<= 1) {
        for (int j = k >> 1; j > 0; j >>= 1) {
            int ixj = t ^ j;
            if (ixj > t) {
                ULL ka = skey[t], kb = skey[ixj];
                int ia = sidx[t], ib = sidx[ixj];
                bool up = ((t & k) == 0);
                bool gt = (ka > kb) || (ka == kb && ia > ib);
                bool lt = (ka < kb) || (ka == kb && ia < ib);
                if (up ? gt : lt) {
                    skey[t] = kb; skey[ixj] = ka;
                    sidx[t] = ib; sidx[ixj] = ia;
                }
            }
            __syncthreads();
        }
    }
    if (t < 1000) selidx[b * 1000 + t] = sidx[t];
}

// ---------------- kernel 5: reg head (fp64) for selected anchors + decode + clip ------------
__global__ __launch_bounds__(256) void decode_boxes(
    const double* __restrict__ y, const int* __restrict__ selidx,
    const float* __restrict__ wregp, const float* __restrict__ bregp,
    const float* __restrict__ anchors, double4* __restrict__ boxes)
{
    __shared__ float wl[9216];
    __shared__ float bl[36];
    for (int i = threadIdx.x; i < 9216; i += 256) wl[i] = wregp[i];
    if (threadIdx.x < 36) bl[threadIdx.x] = bregp[threadIdx.x];
    __syncthreads();
    int gid = blockIdx.x * 256 + threadIdx.x;
    if (gid >= 8000) return;
    int b = gid / 1000;
    int n = selidx[gid];
    int a = n % 9;
    int pix = n / 9;
    const double4* x4 = (const double4*)(y + ((size_t)(b * 4096 + pix)) * 256);
    const float4* w4 = (const float4*)wl;
    double a0 = 0.0, a1 = 0.0, a2 = 0.0, a3 = 0.0;
#pragma unroll 4
    for (int c4 = 0; c4 < 64; c4++) {
        double4 xv = x4[c4];
        float4 w0 = w4[(4 * a + 0) * 64 + c4];
        float4 w1 = w4[(4 * a + 1) * 64 + c4];
        float4 w2 = w4[(4 * a + 2) * 64 + c4];
        float4 w3 = w4[(4 * a + 3) * 64 + c4];
        a0 = fma((double)w0.x, xv.x, a0); a0 = fma((double)w0.y, xv.y, a0);
        a0 = fma((double)w0.z, xv.z, a0); a0 = fma((double)w0.w, xv.w, a0);
        a1 = fma((double)w1.x, xv.x, a1); a1 = fma((double)w1.y, xv.y, a1);
        a1 = fma((double)w1.z, xv.z, a1); a1 = fma((double)w1.w, xv.w, a1);
        a2 = fma((double)w2.x, xv.x, a2); a2 = fma((double)w2.y, xv.y, a2);
        a2 = fma((double)w2.z, xv.z, a2); a2 = fma((double)w2.w, xv.w, a2);
        a3 = fma((double)w3.x, xv.x, a3); a3 = fma((double)w3.y, xv.y, a3);
        a3 = fma((double)w3.z, xv.z, a3); a3 = fma((double)w3.w, xv.w, a3);
    }
    a0 += (double)bl[4 * a + 0]; a1 += (double)bl[4 * a + 1];
    a2 += (double)bl[4 * a + 2]; a3 += (double)bl[4 * a + 3];
    float4 an = ((const float4*)anchors)[n];
    double ax1 = an.x, ay1 = an.y, ax2 = an.z, ay2 = an.w;
    double aw = ax2 - ax1, ah = ay2 - ay1;
    double cx = 0.5 * (ax1 + ax2), cy = 0.5 * (ay1 + ay2);
    double pcx = a0 * aw + cx, pcy = a1 * ah + cy;
    double pw = exp(a2) * aw, ph = exp(a3) * ah;
    double x1b = pcx - 0.5 * pw, y1b = pcy - 0.5 * ph;
    double x2b = pcx + 0.5 * pw, y2b = pcy + 0.5 * ph;
    x1b = fmin(fmax(x1b, 0.0), 1023.0);
    y1b = fmin(fmax(y1b, 0.0), 1023.0);
    x2b = fmin(fmax(x2b, 0.0), 1023.0);
    y2b = fmin(fmax(y2b, 0.0), 1023.0);
    double4 o; o.x = x1b; o.y = y1b; o.z = x2b; o.w = y2b;
    boxes[gid] = o;
}

// ---------------- kernel 6: NMS suppression bitmask matrix (fp64 IoU) -----------------------
__global__ __launch_bounds__(1024) void nms_mask_k(
    const double4* __restrict__ boxes, ULL* __restrict__ mask)
{
    int b = blockIdx.x >> 3;
    int sub = blockIdx.x & 7;
    __shared__ double4 bx[1000];
    for (int i = threadIdx.x; i < 1000; i += 1024) bx[i] = boxes[b * 1000 + i];
    __syncthreads();
    for (int ml = threadIdx.x; ml < 2000; ml += 1024) {
        int m = sub * 2000 + ml;
        int i = m >> 4;
        int wc = m & 15;
        ULL bits = 0ull;
        int j0 = wc << 6;
        if (j0 + 63 > i) {
            double4 bi = bx[i];
            double ai = (bi.z - bi.x) * (bi.w - bi.y);
            int js = max(j0, i + 1);
            int je = min(j0 + 64, 1000);
            for (int j = js; j < je; j++) {
                double4 bj = bx[j];
                double lx = fmax(bi.x, bj.x), ly = fmax(bi.y, bj.y);
                double ux = fmin(bi.z, bj.z), uy = fmin(bi.w, bj.w);
                double iw = fmax(ux - lx, 0.0), ih = fmax(uy - ly, 0.0);
                double inter = iw * ih;
                double aj = (bj.z - bj.x) * (bj.w - bj.y);
                double iou = inter / (ai + aj - inter);
                if (iou > 0.7) bits |= (1ull << (j - j0));
            }
        }
        mask[(size_t)b * 16000 + m] = bits;
    }
}

// ---------------- kernel 7: sequential greedy scan + compaction ----------------------------
__global__ __launch_bounds__(1024) void nms_scan_k(
    const ULL* __restrict__ mask, const double4* __restrict__ boxes,
    float* __restrict__ out)
{
    int b = blockIdx.x;
    int t = threadIdx.x;
    __shared__ ULL keepw[16];
    if (t < 64) {           // wave 0 only
        int lane = t;
        const ULL* mrow = mask + (size_t)b * 16000;
        ULL remv = 0ull, cur = 0ull;
        ULL pf[16];
#pragma unroll
        for (int q = 0; q < 16; q++) pf[q] = (lane < 16) ? mrow[q * 16 + lane] : 0ull;
#pragma unroll 16
        for (int i = 0; i < 1000; i++) {
            ULL m = pf[i & 15];
            if (i + 16 < 1000) pf[i & 15] = (lane < 16) ? mrow[(i + 16) * 16 + lane] : 0ull;
            int c = i >> 6;
            ULL mc = __shfl(m, c);
            bool rem = ((cur >> (i & 63)) & 1ull) != 0ull;
            if (!rem) { remv |= m; cur |= mc; }
            if (((i + 1) & 63) == 0) cur = __shfl(remv, (i + 1) >> 6);
        }
        if (lane < 16) keepw[lane] = ~remv;
    }
    __syncthreads();
    if (t < 300) {
        float* row = out + (size_t)(b * 300 + t) * 5;
        row[0] = (float)b; row[1] = 0.f; row[2] = 0.f; row[3] = 0.f; row[4] = 0.f;
    }
    __syncthreads();
    if (t < 1000) {
        ULL kw = keepw[t >> 6];
        if ((kw >> (t & 63)) & 1ull) {
            int pos = (int)__popcll(kw & ((1ull << (t & 63)) - 1ull));
            for (int w = 0; w < (t >> 6); w++) pos += (int)__popcll(keepw[w]);
            if (pos < 300) {
                double4 bv = boxes[b * 1000 + t];
                float* row = out + (size_t)(b * 300 + pos) * 5;
                row[1] = (float)bv.x; row[2] = (float)bv.y;
                row[3] = (float)bv.z; row[4] = (float)bv.w;
            }
        }
    }
}

// ---------------- launcher ----------------
extern "C" void kernel_launch(void* const* d_in, const int* in_sizes, int n_in,
                              void* d_out, int out_size, void* d_ws, size_t ws_size,
                              hipStream_t stream)
{
    const float* xin     = (const float*)d_in[0];
    const float* anchors = (const float*)d_in[2];
    const float* wconv   = (const float*)d_in[3];
    const float* bconv   = (const float*)d_in[4];
    const float* wclf    = (const float*)d_in[5];
    const float* bclf    = (const float*)d_in[6];
    const float* wregp   = (const float*)d_in[7];
    const float* bregp   = (const float*)d_in[8];
    float* out = (float*)d_out;

    char* base = (char*)d_ws;
    double*  y      = (double*)(base);              // 67,108,864 B
    float*   wt     = (float*)(base + 67108864);    //  2,359,296 B
    double*  dlog   = (double*)(base + 69468160);   //  2,359,296 B
    double4* boxes  = (double4*)(base + 71827456);  //    256,000 B
    ULL*     mask   = (ULL*)(base + 72083456);      //  1,024,000 B
    int*     selidx = (int*)(base + 73107456);      //     32,000 B  (total ~73.2 MB)

    prep_wt<<<2304, 256, 0, stream>>>(wconv, wt);
    conv3x3_relu_f64<<<1024, 256, 0, stream>>>(xin, wt, bconv, y);
    head_clf<<<512, 64, 0, stream>>>(y, wclf, bclf, dlog);
    topk1000<<<8, 1024, 0, stream>>>(dlog, selidx);
    decode_boxes<<<32, 256, 0, stream>>>(y, selidx, wregp, bregp, anchors, boxes);
    nms_mask_k<<<64, 1024, 0, stream>>>(boxes, mask);
    nms_scan_k<<<8, 1024, 0, stream>>>(mask, boxes, out);
}